// Round 7
// baseline (272.329 us; speedup 1.0000x reference)
//
#include <hip/hip_runtime.h>
#include <hip/hip_bf16.h>

#define BATCH 16
#define CIN 64
#define COUT 64
#define HH 160
#define WW 160
#define HP 162
#define WP 162

#define ABUF 21760  // shorts per A buffer: 340 pixels * 64 ch (43,520 B)
#define PSTR 161    // prep LDS row stride (floats); odd => conflict-free reads

typedef __attribute__((ext_vector_type(8))) __bf16 bf16x8;
typedef __attribute__((ext_vector_type(4))) float f32x4;
typedef __attribute__((ext_vector_type(16))) float f32x16;
typedef __attribute__((ext_vector_type(8))) unsigned short ushort8;

typedef __attribute__((address_space(1))) const unsigned int gu32;
typedef __attribute__((address_space(3))) unsigned int lu32;

// ---------------------------------------------------------------------------
// Pass 1 (unchanged, harness-verified): x (NCHW fp32) -> xs (B,162,162,64)
// bf16 with shift folded in; weight cvt in trailing blocks.
// ---------------------------------------------------------------------------
__global__ __launch_bounds__(256) void prep(const float* __restrict__ x,
                                            const float* __restrict__ w,
                                            unsigned short* __restrict__ xs,
                                            unsigned short* __restrict__ wb) {
  __shared__ float lds[64 * PSTR];  // 41,216 B

  if (blockIdx.x >= BATCH * HP) {
    int e = (blockIdx.x - BATCH * HP) * 256 + threadIdx.x;
    if (e < 9 * 64 * 64) {
      int tap = e >> 12;
      int o = (e >> 6) & 63;
      int c = e & 63;
      float v = w[((size_t)(o * 64 + c)) * 9 + tap];
      __hip_bfloat16 h = __float2bfloat16(v);
      wb[e] = *reinterpret_cast<unsigned short*>(&h);
    }
    return;
  }

  int y = blockIdx.x % HP;
  int b = blockIdx.x / HP;
  int tid = threadIdx.x;

  // ---- load: global (coalesced along W) -> LDS, plain layout ----
#pragma unroll
  for (int it = 0; it < 10; ++it) {
    int idx = it * 256 + tid;  // 0..2559 = 64 ch x 40 f32x4
    int c = idx / 40;
    int j = idx - c * 40;
    int cm = c % 5;
    int dy = (cm == 2) ? 1 : ((cm == 4) ? -1 : 0);
    int yy = y - dy;  // source row (1..160 valid)
    f32x4 v = {0.f, 0.f, 0.f, 0.f};
    if (yy >= 1 && yy <= HH)
      v = *reinterpret_cast<const f32x4*>(
          x + (((size_t)(b * CIN + c)) * HH + (size_t)(yy - 1)) * WW + j * 4);
    int p0 = c * PSTR + 4 * j;
#pragma unroll
    for (int e = 0; e < 4; ++e) lds[p0 + e] = v[e];
  }
  __syncthreads();

  // ---- store: fixed 8-channel group per thread, 16B stores ----
  int cg = tid & 7;   // channel group: channels cg*8 .. cg*8+7
  int xr = tid >> 3;  // xi = it*32 + xr
  int dxe[8], rowb[8];
#pragma unroll
  for (int e = 0; e < 8; ++e) {
    int c = cg * 8 + e;
    int cm = c % 5;
    dxe[e] = (cm == 1) ? 1 : ((cm == 3) ? -1 : 0);
    rowb[e] = c * PSTR;
  }
  size_t obase = ((size_t)(b * HP + y) * WP) * CIN + cg * 8;
#pragma unroll
  for (int it = 0; it < 6; ++it) {
    int xi = it * 32 + xr;
    if (xi < WP) {
      ushort8 val;
#pragma unroll
      for (int e = 0; e < 8; ++e) {
        int xx = xi - dxe[e] - 1;  // source x (0..159 valid)
        float v = 0.f;
        if (xx >= 0 && xx < WW) v = lds[rowb[e] + xx];
        __hip_bfloat16 h = __float2bfloat16(v);
        val[e] = *reinterpret_cast<unsigned short*>(&h);
      }
      *reinterpret_cast<ushort8*>(xs + obase + (size_t)xi * CIN) = val;
    }
  }
}

// ---------------------------------------------------------------------------
// Pass 2 (v10): PERSISTENT pipelined implicit-GEMM conv, 32x32x16 MFMA.
//  - 256 blocks (1/CU), 1024 threads = 16 waves = 4/SIMD (R6-best TLP).
//  - LDS: A dbuf 2x43,520 + W 73,728 = 160,768 B.
//  - 16 waves = 8 rows x 2 och-groups(32). Each wave: per tap, 4 A + 4 B
//    ds_read_b128 (4 K-steps of 16ch) + 4 mfma_32x32x16 accumulating into
//    ONE f32x16 acc. Same LDS-read floor as R6 but HALF the MFMA instrs
//    and ~35% fewer issue slots in the dependency chain.
//  - BALANCED CONTIGUOUS tile map: block k owns tiles [6k + min(k,64) ..),
//    7-tile blocks spread 8 per XCD (was: all on XCD 0-1); consecutive
//    tiles are spatially adjacent -> halo L2 hits.
//  - MFMA 32x32 C layout (m74/m101-verified): col(n=och)=lane&31,
//    row(m=x)=(reg&3)+8*(reg>>2)+4*(lane>>5). A/B k-split: k=(lane>>5)*8+j.
//  - Chunk-XOR involutions on A (pix&7) and W (o&7) unchanged (0 conflicts).
// ---------------------------------------------------------------------------
__global__ __launch_bounds__(1024, 4) void conv_mfma(const unsigned short* __restrict__ xs,
                                                     const unsigned short* __restrict__ wb,
                                                     float* __restrict__ out) {
  __shared__ __align__(16) unsigned short lds_a[ABUF];         // 43,520 B
  __shared__ __align__(16) unsigned short lds_b[ABUF];         // 43,520 B
  __shared__ __align__(16) unsigned short lds_w[9 * 64 * 64];  // 73,728 B

  int tid = threadIdx.x;
  int blk = blockIdx.x;
  int start = blk * 6 + (blk < 64 ? blk : 64);  // contiguous, balanced
  int ntiles = 6 + (blk < 64 ? 1 : 0);          // 64*7 + 192*6 = 1600

  int wv = tid >> 6;   // 0..15
  int rw = wv >> 1;    // output row within tile 0..7
  int og = wv & 1;     // och group of 32
  int lane = tid & 63;
  int m31 = lane & 31;  // m (x-position) / n (och offset)
  int q2 = lane >> 5;   // k-half selector
  int l7 = lane & 7;

  int pbase = rw * 34 + m31;           // A pixel base (add ky*34+kx)
  int bwl = (og * 32 + m31) * 64;      // B row base in lds_w (shorts)

  // tile-invariant per-thread A-staging source offsets (shorts)
  int goff[3];
#pragma unroll
  for (int r = 0; r < 3; ++r) {
    int u = r * 1024 + tid;         // chunk index (valid < 2720)
    int p = u >> 3;                 // pixel
    int j = (u & 7) ^ (p & 7);      // source chunk (inverse swizzle)
    int pr = p / 34, pc = p - pr * 34;
    goff[r] = (pr * WP + pc) * CIN + j * 8;
  }

#define STAGE_TO(BUFARR, T_)                                                   \
  {                                                                            \
    int sb_ = (T_) / 100;                                                      \
    int srr_ = (T_) - sb_ * 100;                                               \
    int sti_ = srr_ / 5, stj_ = srr_ - sti_ * 5;                               \
    const unsigned short* srcb_ = xs +                                         \
        ((size_t)sb_ * HP + (size_t)(sti_ * 8)) * WP * CIN +                   \
        (size_t)(stj_ * 32) * CIN;                                             \
    _Pragma("unroll") for (int r = 0; r < 3; ++r) {                            \
      int u_ = r * 1024 + tid;                                                 \
      if (u_ < 2720)                                                           \
        __builtin_amdgcn_global_load_lds((gu32*)(srcb_ + goff[r]),             \
                                         (lu32*)((BUFARR) + (u_ & ~63) * 8),   \
                                         16, 0, 0);                            \
    }                                                                          \
  }

#define LOAD_AB(RBUF, bufp, tt)                                                \
  {                                                                            \
    const int ky_ = (tt) / 3, kx_ = (tt) % 3;                                  \
    int pix_ = pbase + ky_ * 34 + kx_;                                         \
    int px7_ = pix_ & 7;                                                       \
    _Pragma("unroll") for (int ks = 0; ks < 4; ++ks) {                         \
      int ca_ = (ks * 2 + q2) ^ px7_;                                          \
      Ab[bufp][ks] = *reinterpret_cast<const bf16x8*>(                         \
          &(RBUF)[pix_ * 64 + ca_ * 8]);                                       \
      int cb_ = (ks * 2 + q2) ^ l7;                                            \
      Bb[bufp][ks] = *reinterpret_cast<const bf16x8*>(                         \
          &lds_w[(tt) * 4096 + bwl + cb_ * 8]);                                \
    }                                                                          \
  }

#define TILE_BODY(I_, RBUF, WBUF)                                              \
  {                                                                            \
    int t_ = start + (I_);                                                     \
    int b_ = t_ / 100;                                                         \
    int rr_ = t_ - b_ * 100;                                                   \
    int ti_ = rr_ / 5, tj_ = rr_ - ti_ * 5;                                    \
    int y0_ = ti_ * 8, x0_ = tj_ * 32;                                         \
    if ((I_) + 1 < ntiles) STAGE_TO(WBUF, start + (I_) + 1);                   \
    _Pragma("unroll") for (int e_ = 0; e_ < 16; ++e_) acc[e_] = 0.f;           \
    LOAD_AB(RBUF, 0, 0);                                                       \
    _Pragma("unroll") for (int tt = 0; tt < 9; ++tt) {                         \
      if (tt + 1 < 9) LOAD_AB(RBUF, (tt + 1) & 1, tt + 1);                     \
      __builtin_amdgcn_s_setprio(1);                                           \
      _Pragma("unroll") for (int ks = 0; ks < 4; ++ks)                         \
          acc = __builtin_amdgcn_mfma_f32_32x32x16_bf16(                       \
              Ab[tt & 1][ks], Bb[tt & 1][ks], acc, 0, 0, 0);                   \
      __builtin_amdgcn_s_setprio(0);                                           \
    }                                                                          \
    __syncthreads();                                                           \
    int orow_ = y0_ + rw;                                                      \
    int obch_ = og * 32 + m31;                                                 \
    _Pragma("unroll") for (int g = 0; g < 4; ++g) {                            \
      f32x4 v_ = {acc[4 * g], acc[4 * g + 1], acc[4 * g + 2], acc[4 * g + 3]}; \
      int xo_ = x0_ + g * 8 + q2 * 4;                                          \
      *reinterpret_cast<f32x4*>(                                               \
          out + ((size_t)(b_ * COUT + obch_) * HH + (size_t)orow_) * WW +      \
          xo_) = v_;                                                           \
    }                                                                          \
  }

  f32x16 acc;
  bf16x8 Ab[2][4];
  bf16x8 Bb[2][4];

  // ---- prologue: stage weights (once) + tile0, one barrier ----
  // weights: 4608 chunks; lds chunk u holds global chunk (u&7)^(orow&7)
  // of o-row orow=u>>3 (the read-side involution).
#pragma unroll
  for (int r = 0; r < 5; ++r) {
    int u = r * 1024 + tid;
    if (u < 4608) {
      int orow = u >> 3;
      int jj = (u & 7) ^ (orow & 7);
      __builtin_amdgcn_global_load_lds((gu32*)(wb + orow * 64 + jj * 8),
                                       (lu32*)(lds_w + (u & ~63) * 8), 16, 0, 0);
    }
  }
  STAGE_TO(lds_a, start);
  __syncthreads();

  for (int i = 0; i < ntiles; i += 2) {
    TILE_BODY(i, lds_a, lds_b);
    if (i + 1 < ntiles) TILE_BODY(i + 1, lds_b, lds_a);
  }

#undef TILE_BODY
#undef LOAD_AB
#undef STAGE_TO
}

extern "C" void kernel_launch(void* const* d_in, const int* in_sizes, int n_in,
                              void* d_out, int out_size, void* d_ws, size_t ws_size,
                              hipStream_t stream) {
  const float* x = (const float*)d_in[0];
  const float* w = (const float*)d_in[1];
  float* out = (float*)d_out;

  unsigned short* xs = (unsigned short*)d_ws;  // 16*162*162*64 bf16 = 53.7 MB
  unsigned short* wb = (unsigned short*)((char*)d_ws + (size_t)BATCH * HP * WP * CIN * 2);

  hipLaunchKernelGGL(prep, dim3(BATCH * HP + 144), dim3(256), 0, stream, x, w, xs, wb);
  hipLaunchKernelGGL(conv_mfma, dim3(256), dim3(1024), 0, stream, xs, wb, out);
}

// Round 8
// 226.063 us; speedup vs baseline: 1.2047x; 1.2047x over previous
//
#include <hip/hip_runtime.h>
#include <hip/hip_bf16.h>

#define BATCH 16
#define CIN 64
#define COUT 64
#define HH 160
#define WW 160
#define HP 162
#define WP 162

#define ABUF 21760  // shorts per A buffer: 340 pixels * 64 ch (43,520 B)
#define PSTR 161    // prep LDS row stride (floats); odd => conflict-free reads

typedef __attribute__((ext_vector_type(8))) __bf16 bf16x8;
typedef __attribute__((ext_vector_type(4))) float f32x4;
typedef __attribute__((ext_vector_type(8))) unsigned short ushort8;

typedef __attribute__((address_space(1))) const unsigned int gu32;
typedef __attribute__((address_space(3))) unsigned int lu32;

// ---------------------------------------------------------------------------
// Pass 1 (unchanged, harness-verified): x (NCHW fp32) -> xs (B,162,162,64)
// bf16 with shift folded in; weight cvt in trailing blocks.
// ---------------------------------------------------------------------------
__global__ __launch_bounds__(256) void prep(const float* __restrict__ x,
                                            const float* __restrict__ w,
                                            unsigned short* __restrict__ xs,
                                            unsigned short* __restrict__ wb) {
  __shared__ float lds[64 * PSTR];  // 41,216 B

  if (blockIdx.x >= BATCH * HP) {
    int e = (blockIdx.x - BATCH * HP) * 256 + threadIdx.x;
    if (e < 9 * 64 * 64) {
      int tap = e >> 12;
      int o = (e >> 6) & 63;
      int c = e & 63;
      float v = w[((size_t)(o * 64 + c)) * 9 + tap];
      __hip_bfloat16 h = __float2bfloat16(v);
      wb[e] = *reinterpret_cast<unsigned short*>(&h);
    }
    return;
  }

  int y = blockIdx.x % HP;
  int b = blockIdx.x / HP;
  int tid = threadIdx.x;

  // ---- load: global (coalesced along W) -> LDS, plain layout ----
#pragma unroll
  for (int it = 0; it < 10; ++it) {
    int idx = it * 256 + tid;  // 0..2559 = 64 ch x 40 f32x4
    int c = idx / 40;
    int j = idx - c * 40;
    int cm = c % 5;
    int dy = (cm == 2) ? 1 : ((cm == 4) ? -1 : 0);
    int yy = y - dy;  // source row (1..160 valid)
    f32x4 v = {0.f, 0.f, 0.f, 0.f};
    if (yy >= 1 && yy <= HH)
      v = *reinterpret_cast<const f32x4*>(
          x + (((size_t)(b * CIN + c)) * HH + (size_t)(yy - 1)) * WW + j * 4);
    int p0 = c * PSTR + 4 * j;
#pragma unroll
    for (int e = 0; e < 4; ++e) lds[p0 + e] = v[e];
  }
  __syncthreads();

  // ---- store: fixed 8-channel group per thread, 16B stores ----
  int cg = tid & 7;   // channel group: channels cg*8 .. cg*8+7
  int xr = tid >> 3;  // xi = it*32 + xr
  int dxe[8], rowb[8];
#pragma unroll
  for (int e = 0; e < 8; ++e) {
    int c = cg * 8 + e;
    int cm = c % 5;
    dxe[e] = (cm == 1) ? 1 : ((cm == 3) ? -1 : 0);
    rowb[e] = c * PSTR;
  }
  size_t obase = ((size_t)(b * HP + y) * WP) * CIN + cg * 8;
#pragma unroll
  for (int it = 0; it < 6; ++it) {
    int xi = it * 32 + xr;
    if (xi < WP) {
      ushort8 val;
#pragma unroll
      for (int e = 0; e < 8; ++e) {
        int xx = xi - dxe[e] - 1;  // source x (0..159 valid)
        float v = 0.f;
        if (xx >= 0 && xx < WW) v = lds[rowb[e] + xx];
        __hip_bfloat16 h = __float2bfloat16(v);
        val[e] = *reinterpret_cast<unsigned short*>(&h);
      }
      *reinterpret_cast<ushort8*>(xs + obase + (size_t)xi * CIN) = val;
    }
  }
}

// ---------------------------------------------------------------------------
// Pass 2 (v11 = verified v9 + XCD-FAIR straggler assignment ONLY).
//  - R7 lessons: 32x32 fragments span 32 LDS rows -> 4-way bank conflict
//    (7.37M); contiguous tile map breaks XCD-L2 banding (FETCH 94MB) and
//    its epilogue splits 64B lines across stores (WRITE +35MB). Reverted.
//  - Structure = R6: 256 blocks (1/CU), 1024 thr = 16 waves = 4/SIMD,
//    16x16x32 MFMA, weights in LDS, A dbuf, zero-VMEM inner loop,
//    one barrier per tile, chunk-XOR involutions (0 conflicts measured).
//  - ONLY change: R6 gave all 64 seven-tile blocks to XCDs 0-1 (12%
//    straggler tail). Now extras (tiles 1536..1599) go to blk<64 =
//    8 blocks per XCD: textra = 1536 + (blk&7)*8 + (blk>>3). Bijective,
//    XCD-fair; base map (tile0 = (blk&7)*32 + (blk>>3), stride 256, L2
//    banding that measured FETCH 27.6MB) untouched.
// MFMA mapping unchanged (harness-verified): D[row=q*4+reg][col=l15];
// x = x0 + mt*16 + q*4 + reg, o = nh*32 + ns*16 + l15, row = y0 + (wv>>1).
// ---------------------------------------------------------------------------
__global__ __launch_bounds__(1024, 4) void conv_mfma(const unsigned short* __restrict__ xs,
                                                     const unsigned short* __restrict__ wb,
                                                     float* __restrict__ out) {
  __shared__ __align__(16) unsigned short lds_a[ABUF];         // 43,520 B
  __shared__ __align__(16) unsigned short lds_b[ABUF];         // 43,520 B
  __shared__ __align__(16) unsigned short lds_w[9 * 64 * 64];  // 73,728 B

  int tid = threadIdx.x;
  int blk = blockIdx.x;
  int tile0 = (blk & 7) * 32 + (blk >> 3);        // XCD-banded, bijective
  int textra = 1536 + (blk & 7) * 8 + (blk >> 3); // valid only for blk<64
  int ntiles = 6 + (blk < 64 ? 1 : 0);            // 256*6 + 64 = 1600

#define TOF(I_) ((I_) < 6 ? tile0 + 256 * (I_) : textra)

  int wv = tid >> 6;   // 0..15
  int rw = wv >> 1;    // output row within tile 0..7
  int nh = wv & 1;     // och half
  int lane = tid & 63;
  int l15 = lane & 15;
  int q = lane >> 4;

  // tile-invariant per-thread A-staging source offsets (shorts)
  int goff[3];
#pragma unroll
  for (int r = 0; r < 3; ++r) {
    int u = r * 1024 + tid;         // chunk index (valid < 2720)
    int p = u >> 3;                 // pixel
    int j = (u & 7) ^ (p & 7);      // source chunk (inverse swizzle)
    int pr = p / 34, pc = p - pr * 34;
    goff[r] = (pr * WP + pc) * CIN + j * 8;
  }

  // per-lane B bases in lds_w (shorts): chunk' = (ch*4+q) ^ (l15&7)
  int bw0 = l15 * 64 + ((q ^ (l15 & 7)) * 8);        // ch = 0
  int bw1 = l15 * 64 + (((4 + q) ^ (l15 & 7)) * 8);  // ch = 1

#define STAGE_TO(BUFARR, T_)                                                   \
  {                                                                            \
    int sb_ = (T_) / 100;                                                      \
    int srr_ = (T_) - sb_ * 100;                                               \
    int sti_ = srr_ / 5, stj_ = srr_ - sti_ * 5;                               \
    const unsigned short* srcb_ = xs +                                         \
        ((size_t)sb_ * HP + (size_t)(sti_ * 8)) * WP * CIN +                   \
        (size_t)(stj_ * 32) * CIN;                                             \
    _Pragma("unroll") for (int r = 0; r < 3; ++r) {                            \
      int u_ = r * 1024 + tid;                                                 \
      if (u_ < 2720)                                                           \
        __builtin_amdgcn_global_load_lds((gu32*)(srcb_ + goff[r]),             \
                                         (lu32*)((BUFARR) + (u_ & ~63) * 8),   \
                                         16, 0, 0);                            \
    }                                                                          \
  }

#define LOAD_A(RBUF, bufp, tt)                                                 \
  {                                                                            \
    const int ch_ = (tt) / 9, ky_ = ((tt) % 9) / 3, kx_ = (tt) % 3;            \
    _Pragma("unroll") for (int mt = 0; mt < 2; ++mt) {                         \
      int pix = (rw + ky_) * 34 + kx_ + l15 + mt * 16;                         \
      int chunk = (ch_ * 4 + q) ^ (pix & 7);                                   \
      Ab[bufp][mt] =                                                           \
          *reinterpret_cast<const bf16x8*>(&(RBUF)[pix * 64 + chunk * 8]);     \
    }                                                                          \
  }

#define LOAD_BW(bufp, tt)                                                      \
  {                                                                            \
    const int ch_ = (tt) / 9, tap_ = (tt) % 9;                                 \
    _Pragma("unroll") for (int ns = 0; ns < 2; ++ns)                           \
        Bb[bufp][ns] = *reinterpret_cast<const bf16x8*>(                       \
            &lds_w[tap_ * 4096 + (nh * 2 + ns) * 1024 + (ch_ ? bw1 : bw0)]);   \
  }

#define TILE_BODY(I_, RBUF, WBUF)                                              \
  {                                                                            \
    int t_ = TOF(I_);                                                          \
    int b_ = t_ / 100;                                                         \
    int rr_ = t_ - b_ * 100;                                                   \
    int ti_ = rr_ / 5, tj_ = rr_ - ti_ * 5;                                    \
    int y0_ = ti_ * 8, x0_ = tj_ * 32;                                         \
    if ((I_) + 1 < ntiles) STAGE_TO(WBUF, TOF((I_) + 1));                      \
    _Pragma("unroll") for (int a_ = 0; a_ < 2; ++a_)                           \
      _Pragma("unroll") for (int c2_ = 0; c2_ < 2; ++c2_)                      \
        acc[a_][c2_] = (f32x4){0.f, 0.f, 0.f, 0.f};                            \
    LOAD_A(RBUF, 0, 0);                                                        \
    LOAD_BW(0, 0);                                                             \
    _Pragma("unroll") for (int tt = 0; tt < 18; ++tt) {                        \
      if (tt + 1 < 18) {                                                       \
        LOAD_A(RBUF, (tt + 1) & 1, tt + 1);                                    \
        LOAD_BW((tt + 1) & 1, tt + 1);                                         \
      }                                                                        \
      __builtin_amdgcn_s_setprio(1);                                           \
      _Pragma("unroll") for (int mt = 0; mt < 2; ++mt)                         \
        _Pragma("unroll") for (int ns = 0; ns < 2; ++ns)                       \
          acc[mt][ns] = __builtin_amdgcn_mfma_f32_16x16x32_bf16(               \
              Ab[tt & 1][mt], Bb[tt & 1][ns], acc[mt][ns], 0, 0, 0);           \
      __builtin_amdgcn_s_setprio(0);                                           \
    }                                                                          \
    __syncthreads();                                                           \
    _Pragma("unroll") for (int mt = 0; mt < 2; ++mt) {                         \
      int orow_ = y0_ + rw;                                                    \
      int xo_ = x0_ + mt * 16 + q * 4;                                         \
      _Pragma("unroll") for (int ns = 0; ns < 2; ++ns) {                       \
        int o_ = nh * 32 + ns * 16 + l15;                                      \
        *reinterpret_cast<f32x4*>(                                             \
            out + ((size_t)(b_ * COUT + o_) * HH + (size_t)orow_) * WW + xo_) = \
            acc[mt][ns];                                                       \
      }                                                                        \
    }                                                                          \
  }

  f32x4 acc[2][2];
  bf16x8 Ab[2][2];
  bf16x8 Bb[2][2];

  // ---- prologue: stage weights (once) + tile0, one barrier ----
  // weights: 4608 chunks; lds chunk u holds global chunk (u&7)^(orow&7)
  // of o-row orow=u>>3 (the read-side involution).
#pragma unroll
  for (int r = 0; r < 5; ++r) {
    int u = r * 1024 + tid;
    if (u < 4608) {
      int orow = u >> 3;
      int jj = (u & 7) ^ (orow & 7);
      __builtin_amdgcn_global_load_lds((gu32*)(wb + orow * 64 + jj * 8),
                                       (lu32*)(lds_w + (u & ~63) * 8), 16, 0, 0);
    }
  }
  STAGE_TO(lds_a, tile0);
  __syncthreads();

  for (int i = 0; i < ntiles; i += 2) {
    TILE_BODY(i, lds_a, lds_b);
    if (i + 1 < ntiles) TILE_BODY(i + 1, lds_b, lds_a);
  }

#undef TILE_BODY
#undef LOAD_BW
#undef LOAD_A
#undef STAGE_TO
#undef TOF
}

extern "C" void kernel_launch(void* const* d_in, const int* in_sizes, int n_in,
                              void* d_out, int out_size, void* d_ws, size_t ws_size,
                              hipStream_t stream) {
  const float* x = (const float*)d_in[0];
  const float* w = (const float*)d_in[1];
  float* out = (float*)d_out;

  unsigned short* xs = (unsigned short*)d_ws;  // 16*162*162*64 bf16 = 53.7 MB
  unsigned short* wb = (unsigned short*)((char*)d_ws + (size_t)BATCH * HP * WP * CIN * 2);

  hipLaunchKernelGGL(prep, dim3(BATCH * HP + 144), dim3(256), 0, stream, x, w, xs, wb);
  hipLaunchKernelGGL(conv_mfma, dim3(256), dim3(1024), 0, stream, xs, wb, out);
}